// Round 5
// baseline (79.163 us; speedup 1.0000x reference)
//
#include <hip/hip_runtime.h>
#include <math.h>

#define SEQ 8192
#define HID 2048
#define NC4 (HID / 4)   // 512 float4 per row
#define VCHUNKS 8       // v row-chunks of 256 rows
#define NBK2 512        // k2 block count

// Workspace (floats):
//   m       [0,     2048)
//   vpart   [2048,  2048 + 8*2048)
//   energ   [18432, 18432 + 8192)
//   counter [26624] (as unsigned)

// ---------------------------------------------------------------------------
// K1: blocks 0..255  -> m[row] = W_pq[row,:].pool + b_pq[row]   (8 rows/block)
//     blocks 256..511-> vpart[rc][:] partials over 256-row chunks (no atomics)
//     block 0 also zeroes k2's completion counter (stream-ordered before k2).
// ---------------------------------------------------------------------------
__global__ __launch_bounds__(256) void k1(const float* __restrict__ pool,
                                          const float* __restrict__ W_pq,
                                          const float* __restrict__ b_pq,
                                          const float* __restrict__ hidden,
                                          const float* __restrict__ W_qh,
                                          float* __restrict__ m,
                                          float* __restrict__ vpart,
                                          unsigned* __restrict__ counter) {
  const int tid  = threadIdx.x;
  const int wave = tid >> 6;
  const int lane = tid & 63;
  const int bid  = blockIdx.x;

  if (bid == 0 && tid == 0) *counter = 0u;

  if (bid < 256) {
    const float4* p4 = reinterpret_cast<const float4*>(pool);
    #pragma unroll
    for (int rr = 0; rr < 2; ++rr) {
      const int row = bid * 8 + wave * 2 + rr;
      const float4* Wrow = reinterpret_cast<const float4*>(W_pq + (size_t)row * HID);
      float acc = 0.f;
      #pragma unroll
      for (int i = lane; i < NC4; i += 64) {
        float4 w = Wrow[i], p = p4[i];
        acc += w.x * p.x + w.y * p.y + w.z * p.z + w.w * p.w;
      }
      #pragma unroll
      for (int off = 32; off; off >>= 1) acc += __shfl_down(acc, off, 64);
      if (lane == 0) m[row] = acc + b_pq[row];
    }
  } else {
    __shared__ float4 part[256];
    const int u  = bid - 256;
    const int ct = u & 31;           // 32 col-tiles x 16 float4
    const int rc = u >> 5;           // 8 row-chunks x 256 rows
    const int c4 = ct * 16 + (tid & 15);
    const int r0 = rc * 256 + (tid >> 4) * 16;
    float4 acc = {0.f, 0.f, 0.f, 0.f};
    #pragma unroll
    for (int i = 0; i < 16; ++i) {
      const int r = r0 + i;
      const float h  = hidden[r];
      const float4 w = reinterpret_cast<const float4*>(W_qh + (size_t)r * HID)[c4];
      acc.x += h * w.x; acc.y += h * w.y; acc.z += h * w.z; acc.w += h * w.w;
    }
    part[tid] = acc;
    __syncthreads();
    if (tid < 16) {
      float4 s = part[tid];
      #pragma unroll
      for (int k = 1; k < 16; ++k) {
        float4 p = part[k * 16 + tid];
        s.x += p.x; s.y += p.y; s.z += p.z; s.w += p.w;
      }
      reinterpret_cast<float4*>(vpart)[rc * NC4 + ct * 16 + tid] = s;
    }
  }
}

// ---------------------------------------------------------------------------
// K2: per block — reduce vpart*m -> g (LDS -> registers), 16 energy rows with
// paired-row ILP, then last-finished block runs the softmax tail inline.
// ---------------------------------------------------------------------------
__global__ __launch_bounds__(256) void k2(const float* __restrict__ enc,
                                          const float* __restrict__ m,
                                          const float* __restrict__ vpart,
                                          float* __restrict__ energ,
                                          unsigned* __restrict__ counter,
                                          float* __restrict__ out) {
  __shared__ float4 gl[NC4];    // 8 KB reduced g
  __shared__ float red[8];
  __shared__ unsigned oldv;
  const int tid  = threadIdx.x;
  const int wave = tid >> 6;
  const int lane = tid & 63;
  const int bid  = blockIdx.x;

  // ---- g = (sum_chunks vpart) * m ----
  const float4* vp = reinterpret_cast<const float4*>(vpart);
  const float4* m4 = reinterpret_cast<const float4*>(m);
  #pragma unroll
  for (int j = 0; j < 2; ++j) {
    const int c = tid + j * 256;
    float4 a = vp[c];
    #pragma unroll
    for (int k = 1; k < VCHUNKS; ++k) {
      float4 p = vp[k * NC4 + c];
      a.x += p.x; a.y += p.y; a.z += p.z; a.w += p.w;
    }
    const float4 mm = m4[c];
    float4 g = {a.x * mm.x, a.y * mm.y, a.z * mm.z, a.w * mm.w};
    gl[c] = g;
  }
  __syncthreads();

  // ---- lane-invariant g slices into registers (reused by all rows) ----
  float4 greg[8];
  #pragma unroll
  for (int j = 0; j < 8; ++j) greg[j] = gl[lane + j * 64];

  // ---- 16 rows/block, 4/wave, processed in pairs for load ILP ----
  #pragma unroll
  for (int rp = 0; rp < 2; ++rp) {
    const int row0 = bid * 16 + wave * 4 + rp * 2;
    const float4* E0 = reinterpret_cast<const float4*>(enc + (size_t)row0 * HID);
    const float4* E1 = reinterpret_cast<const float4*>(enc + (size_t)(row0 + 1) * HID);
    float acc0 = 0.f, acc1 = 0.f;
    #pragma unroll
    for (int j = 0; j < 8; ++j) {
      const int i = lane + j * 64;
      float4 e0 = E0[i], e1 = E1[i], g = greg[j];
      acc0 += e0.x * g.x + e0.y * g.y + e0.z * g.z + e0.w * g.w;
      acc1 += e1.x * g.x + e1.y * g.y + e1.z * g.z + e1.w * g.w;
    }
    #pragma unroll
    for (int off = 32; off; off >>= 1) {
      acc0 += __shfl_down(acc0, off, 64);
      acc1 += __shfl_down(acc1, off, 64);
    }
    if (lane == 0) {
      energ[row0]     = acc0;
      energ[row0 + 1] = acc1;
    }
  }

  // ---- completion count; last block runs the softmax tail ----
  __threadfence();                      // release energ device-wide
  if (tid == 0) oldv = atomicAdd(counter, 1u);
  __syncthreads();
  if (oldv != NBK2 - 1) return;

  __threadfence();                      // acquire all blocks' energ
  float vals[32];
  float mx = -INFINITY;
  #pragma unroll
  for (int i = 0; i < 32; ++i) {
    vals[i] = energ[tid + i * 256];
    mx = fmaxf(mx, vals[i]);
  }
  #pragma unroll
  for (int off = 32; off; off >>= 1) mx = fmaxf(mx, __shfl_down(mx, off, 64));
  if (lane == 0) red[wave] = mx;
  __syncthreads();
  const float bm = fmaxf(fmaxf(red[0], red[1]), fmaxf(red[2], red[3]));

  float s = 0.f;
  #pragma unroll
  for (int i = 0; i < 32; ++i) {
    vals[i] = expf(vals[i] - bm);
    s += vals[i];
  }
  #pragma unroll
  for (int off = 32; off; off >>= 1) s += __shfl_down(s, off, 64);
  if (lane == 0) red[4 + wave] = s;
  __syncthreads();
  const float inv = 1.f / (red[4] + red[5] + red[6] + red[7]);

  #pragma unroll
  for (int i = 0; i < 32; ++i) out[tid + i * 256] = vals[i] * inv;
}

// ---------------------------------------------------------------------------
extern "C" void kernel_launch(void* const* d_in, const int* in_sizes, int n_in,
                              void* d_out, int out_size, void* d_ws, size_t ws_size,
                              hipStream_t stream) {
  const float* hidden = (const float*)d_in[0];  // (1, 2048)
  const float* enc    = (const float*)d_in[1];  // (8192, 2048)
  const float* pool   = (const float*)d_in[2];  // (1, 2048)
  const float* W_pq   = (const float*)d_in[3];  // (2048, 2048)
  const float* b_pq   = (const float*)d_in[4];  // (2048,)
  const float* W_qh   = (const float*)d_in[5];  // (2048, 2048)
  // d_in[6] = b_qh — uniform shift over seq, cancels in softmax.

  float*    out     = (float*)d_out;
  float*    ws      = (float*)d_ws;
  float*    m       = ws;                        // 2048
  float*    vpart   = ws + HID;                  // 8 * 2048
  float*    energ   = ws + HID + VCHUNKS * HID;  // 8192
  unsigned* counter = (unsigned*)(ws + HID + VCHUNKS * HID + SEQ);

  k1<<<dim3(512), dim3(256), 0, stream>>>(pool, W_pq, b_pq, hidden, W_qh,
                                          m, vpart, counter);
  k2<<<dim3(NBK2), dim3(256), 0, stream>>>(enc, m, vpart, energ, counter, out);
}

// Round 6
// 26.964 us; speedup vs baseline: 2.9358x; 2.9358x over previous
//
#include <hip/hip_runtime.h>
#include <math.h>

#define SEQ 8192
#define HID 2048
#define NC4 (HID / 4)   // 512 float4 per row
#define VCHUNKS 8       // v row-chunks of 256 rows

// Workspace (floats):
//   m     [0,     2048)
//   vpart [2048,  2048 + 8*2048)
//   energ [18432, 18432 + 8192)

// ---------------------------------------------------------------------------
// K1: blocks 0..255   -> m[row] = W_pq[row,:].pool + b_pq[row]  (8 rows/block,
//                        one concurrent pair per wave: 16 loads in flight)
//     blocks 256..511 -> vpart[rc][:] partials over 256-row chunks, two
//                        independent 8-row FMA chains per thread (2x ILP)
// ---------------------------------------------------------------------------
__global__ __launch_bounds__(256) void k1(const float* __restrict__ pool,
                                          const float* __restrict__ W_pq,
                                          const float* __restrict__ b_pq,
                                          const float* __restrict__ hidden,
                                          const float* __restrict__ W_qh,
                                          float* __restrict__ m,
                                          float* __restrict__ vpart) {
  const int tid  = threadIdx.x;
  const int wave = tid >> 6;
  const int lane = tid & 63;
  const int bid  = blockIdx.x;

  if (bid < 256) {
    const float4* p4 = reinterpret_cast<const float4*>(pool);
    const int row0 = bid * 8 + wave * 2;
    const float4* W0 = reinterpret_cast<const float4*>(W_pq + (size_t)row0 * HID);
    const float4* W1 = reinterpret_cast<const float4*>(W_pq + (size_t)(row0 + 1) * HID);
    float acc0 = 0.f, acc1 = 0.f;
    #pragma unroll
    for (int j = 0; j < 8; ++j) {
      const int i = lane + j * 64;
      float4 p = p4[i];
      float4 w0 = W0[i], w1 = W1[i];
      acc0 += w0.x * p.x + w0.y * p.y + w0.z * p.z + w0.w * p.w;
      acc1 += w1.x * p.x + w1.y * p.y + w1.z * p.z + w1.w * p.w;
    }
    #pragma unroll
    for (int off = 32; off; off >>= 1) {
      acc0 += __shfl_down(acc0, off, 64);
      acc1 += __shfl_down(acc1, off, 64);
    }
    if (lane == 0) {
      m[row0]     = acc0 + b_pq[row0];
      m[row0 + 1] = acc1 + b_pq[row0 + 1];
    }
  } else {
    __shared__ float4 part[256];
    const int u  = bid - 256;
    const int ct = u & 31;           // 32 col-tiles x 16 float4
    const int rc = u >> 5;           // 8 row-chunks x 256 rows
    const int c4 = ct * 16 + (tid & 15);
    const int r0 = rc * 256 + (tid >> 4) * 16;
    float4 a0 = {0.f, 0.f, 0.f, 0.f};
    float4 a1 = {0.f, 0.f, 0.f, 0.f};
    #pragma unroll
    for (int i = 0; i < 8; ++i) {
      const int ra = r0 + i, rb = r0 + 8 + i;
      const float  ha = hidden[ra],  hb = hidden[rb];
      const float4 wa = reinterpret_cast<const float4*>(W_qh + (size_t)ra * HID)[c4];
      const float4 wb = reinterpret_cast<const float4*>(W_qh + (size_t)rb * HID)[c4];
      a0.x += ha * wa.x; a0.y += ha * wa.y; a0.z += ha * wa.z; a0.w += ha * wa.w;
      a1.x += hb * wb.x; a1.y += hb * wb.y; a1.z += hb * wb.z; a1.w += hb * wb.w;
    }
    a0.x += a1.x; a0.y += a1.y; a0.z += a1.z; a0.w += a1.w;
    part[tid] = a0;
    __syncthreads();
    if (tid < 16) {
      float4 s = part[tid];
      #pragma unroll
      for (int k = 1; k < 16; ++k) {
        float4 p = part[k * 16 + tid];
        s.x += p.x; s.y += p.y; s.z += p.z; s.w += p.w;
      }
      reinterpret_cast<float4*>(vpart)[rc * NC4 + ct * 16 + tid] = s;
    }
  }
}

// ---------------------------------------------------------------------------
// K2: 1024 blocks x 8 rows. Per block: reduce vpart*m -> g (LDS->regs), then
// each wave computes its 2 rows CONCURRENTLY (16 float4 loads in flight).
// ---------------------------------------------------------------------------
__global__ __launch_bounds__(256) void k2(const float* __restrict__ enc,
                                          const float* __restrict__ m,
                                          const float* __restrict__ vpart,
                                          float* __restrict__ energ) {
  __shared__ float4 gl[NC4];    // 8 KB reduced g
  const int tid  = threadIdx.x;
  const int wave = tid >> 6;
  const int lane = tid & 63;
  const int bid  = blockIdx.x;

  // ---- g = (sum_chunks vpart) * m  (L2-hot, every block) ----
  const float4* vp = reinterpret_cast<const float4*>(vpart);
  const float4* m4 = reinterpret_cast<const float4*>(m);
  #pragma unroll
  for (int j = 0; j < 2; ++j) {
    const int c = tid + j * 256;
    float4 a = vp[c];
    #pragma unroll
    for (int k = 1; k < VCHUNKS; ++k) {
      float4 p = vp[k * NC4 + c];
      a.x += p.x; a.y += p.y; a.z += p.z; a.w += p.w;
    }
    const float4 mm = m4[c];
    float4 g = {a.x * mm.x, a.y * mm.y, a.z * mm.z, a.w * mm.w};
    gl[c] = g;
  }
  __syncthreads();

  // ---- lane-invariant g slices in registers (reused by both rows) ----
  float4 greg[8];
  #pragma unroll
  for (int j = 0; j < 8; ++j) greg[j] = gl[lane + j * 64];

  // ---- 8 rows/block, one concurrent pair per wave ----
  const int row0 = bid * 8 + wave * 2;
  const float4* E0 = reinterpret_cast<const float4*>(enc + (size_t)row0 * HID);
  const float4* E1 = reinterpret_cast<const float4*>(enc + (size_t)(row0 + 1) * HID);
  float acc0 = 0.f, acc1 = 0.f;
  #pragma unroll
  for (int j = 0; j < 8; ++j) {
    const int i = lane + j * 64;
    float4 e0 = E0[i], e1 = E1[i], g = greg[j];
    acc0 += e0.x * g.x + e0.y * g.y + e0.z * g.z + e0.w * g.w;
    acc1 += e1.x * g.x + e1.y * g.y + e1.z * g.z + e1.w * g.w;
  }
  #pragma unroll
  for (int off = 32; off; off >>= 1) {
    acc0 += __shfl_down(acc0, off, 64);
    acc1 += __shfl_down(acc1, off, 64);
  }
  if (lane == 0) {
    energ[row0]     = acc0;
    energ[row0 + 1] = acc1;
  }
}

// ---------------------------------------------------------------------------
// K3: softmax — 32 blocks, each redundantly computes the identical global
// max/sum (bit-identical order), writes its own 256 outputs. No 1-CU tail.
// ---------------------------------------------------------------------------
__global__ __launch_bounds__(256) void k3(const float* __restrict__ e,
                                          float* __restrict__ out) {
  __shared__ float red[8];
  const int tid  = threadIdx.x;
  const int wave = tid >> 6;
  const int lane = tid & 63;
  const int bid  = blockIdx.x;

  float vals[32];
  float mx = -INFINITY;
  #pragma unroll
  for (int i = 0; i < 32; ++i) {
    vals[i] = e[tid + i * 256];
    mx = fmaxf(mx, vals[i]);
  }
  #pragma unroll
  for (int off = 32; off; off >>= 1) mx = fmaxf(mx, __shfl_down(mx, off, 64));
  if (lane == 0) red[wave] = mx;
  __syncthreads();
  const float bm = fmaxf(fmaxf(red[0], red[1]), fmaxf(red[2], red[3]));

  float s = 0.f;
  #pragma unroll
  for (int i = 0; i < 32; ++i) s += expf(vals[i] - bm);
  #pragma unroll
  for (int off = 32; off; off >>= 1) s += __shfl_down(s, off, 64);
  if (lane == 0) red[4 + wave] = s;
  __syncthreads();
  const float inv = 1.f / (red[4] + red[5] + red[6] + red[7]);

  const int row = bid * 256 + tid;
  out[row] = expf(e[row] - bm) * inv;
}

// ---------------------------------------------------------------------------
extern "C" void kernel_launch(void* const* d_in, const int* in_sizes, int n_in,
                              void* d_out, int out_size, void* d_ws, size_t ws_size,
                              hipStream_t stream) {
  const float* hidden = (const float*)d_in[0];  // (1, 2048)
  const float* enc    = (const float*)d_in[1];  // (8192, 2048)
  const float* pool   = (const float*)d_in[2];  // (1, 2048)
  const float* W_pq   = (const float*)d_in[3];  // (2048, 2048)
  const float* b_pq   = (const float*)d_in[4];  // (2048,)
  const float* W_qh   = (const float*)d_in[5];  // (2048, 2048)
  // d_in[6] = b_qh — uniform shift over seq, cancels in softmax.

  float* out   = (float*)d_out;
  float* ws    = (float*)d_ws;
  float* m     = ws;                       // 2048
  float* vpart = ws + HID;                 // 8 * 2048
  float* energ = ws + HID + VCHUNKS * HID; // 8192

  k1<<<dim3(512), dim3(256), 0, stream>>>(pool, W_pq, b_pq, hidden, W_qh, m, vpart);
  k2<<<dim3(1024), dim3(256), 0, stream>>>(enc, m, vpart, energ);
  k3<<<dim3(32), dim3(256), 0, stream>>>(energ, out);
}